// Round 1
// 708.628 us; speedup vs baseline: 1.1200x; 1.1200x over previous
//
#include <hip/hip_runtime.h>

// LinearAttention on MI355X (gfx950), bf16 MFMA pipeline.
// R3: GEMM1 + GEMM3 moved to a 256x256-tile 8-phase software-pipelined kernel
// (HK-style schedule in plain HIP: raw s_barrier, counted vmcnt(6), XOR-swizzled
// LDS reads with inverse-swizzled global_load_lds source, s_setprio around MFMA
// clusters). GEMM2/2b keep the 128^2 kernel (their grids are too small for 256^2).

#define EPS 1e-6f

using u16 = unsigned short;
typedef __attribute__((ext_vector_type(4))) float f32x4;
typedef __attribute__((ext_vector_type(8))) __bf16 bf16x8;

__device__ __forceinline__ u16 f2b(float f) {
  unsigned u = __builtin_bit_cast(unsigned, f);
  u += 0x7FFFu + ((u >> 16) & 1u);     // RNE
  return (u16)(u >> 16);
}
__device__ __forceinline__ float b2f(u16 h) {
  return __builtin_bit_cast(float, (unsigned)h << 16);
}

typedef const __attribute__((address_space(1))) void* gas1_t;
typedef __attribute__((address_space(3))) void* las3_t;

__device__ __forceinline__ void load16_to_lds(const void* g, void* l) {
  __builtin_amdgcn_global_load_lds((gas1_t)g, (las3_t)l, 16, 0, 0);
}

#define BARRIER() do { asm volatile("" ::: "memory"); __builtin_amdgcn_s_barrier(); asm volatile("" ::: "memory"); } while (0)
#define WAITL0()  asm volatile("s_waitcnt lgkmcnt(0)" ::: "memory")
#define WAITV(n)  asm volatile("s_waitcnt vmcnt(" #n ")" ::: "memory")
#define MFMA16(a, b, c) __builtin_amdgcn_mfma_f32_16x16x32_bf16((a), (b), (c), 0, 0, 0)

// Stage one 128x64 half-tile: LDS dest linear (global_load_lds requirement),
// global source column pre-swizzled with the involution chunk ^= (row&7) so the
// swizzled ds_read side reads the right bytes (rule: both-sides-or-neither).
__device__ __forceinline__ void stage_half(const u16* g, int ld, u16* l,
                                           int r0, int csw, int woff) {
  load16_to_lds(g + (long long)r0 * ld + csw, l + woff);
  load16_to_lds(g + (long long)(r0 + 64) * ld + csw, l + 4096 + woff);
}

// ---------------------------------------------------------------------------
// 256x256-tile, BK=64, 8 waves (2M x 4N), double-buffered 128 KiB LDS,
// 4 phases per K-tile, counted vmcnt(6) (3 half-tiles always in flight).
// C = A * B^T.  A: [M][K] bf16, B: [N][K] bf16. Batched via z.
// MODE 0: GEMM1 fused epilogue (q n-major relu+eps / kT,vT transposed / ksum).
// MODE 1: bf16 out.  MODE 2: f32 out, v*z[row] + bias[col].
// Requires M%256==0, N%256==0, K%64==0, (gridDim.x*gridDim.y)%8==0.
// ---------------------------------------------------------------------------
template<int MODE>
__global__ __launch_bounds__(512, 2) void gemm256(
    const u16* __restrict__ A, const u16* __restrict__ B, void* __restrict__ Cv,
    int M, int N, int K, int lda, int ldb, int ldc,
    long long sA, long long sB, long long sC,
    const float* __restrict__ zvec, const float* __restrict__ bias,
    u16* __restrict__ kT, u16* __restrict__ vT, float* __restrict__ ksum)
{
  __shared__ __align__(16) u16 shA[32768];   // [2 buf][2 half][128 r][8 chunks*8]
  __shared__ __align__(16) u16 shB[32768];

  const int tid  = threadIdx.x;
  const int lane = tid & 63, wave = tid >> 6;
  const int wr = wave >> 2, wc = wave & 3;           // 2M x 4N wave grid
  const int quad = lane >> 4, lc = lane & 15;

  // XCD-aware swizzle (bijective: grid multiple of 8)
  const int TN = gridDim.y;
  const int lin = blockIdx.x + gridDim.x * blockIdx.y;
  const int xcd = lin & 7, g = lin >> 3;
  const int bm = (g / TN) * 8 + xcd;
  const int bn = g % TN;
  const int bz = blockIdx.z;
  const u16* Ab = A + (long long)bz * sA;
  const u16* Bb = B + (long long)bz * sB;

  // staging addressing: thread covers chunks {tid, 512+tid} of each half-tile
  const int r0   = tid >> 3;                                   // rows 0..63 (+64)
  const int csw  = (((tid & 7) ^ ((tid >> 3) & 7)) << 3);      // inverse-swz col
  const int woff = wave * 512;                                 // wave-uniform LDS off

  // fragment read addressing (swizzled chunk index, constant per lane)
  const int ch0 = ((quad ^ (lane & 7)) << 3);                  // ksub 0
  const int ch1 = (((4 + quad) ^ (lane & 7)) << 3);            // ksub 1
  const int aRow = wr * 128 + lc;
  const int bRow = wc * 64 + lc;

  const int NT = K >> 6;

  f32x4 acc[8][4];
  #pragma unroll
  for (int i = 0; i < 8; ++i)
    #pragma unroll
    for (int j = 0; j < 4; ++j) acc[i][j] = f32x4{0.f, 0.f, 0.f, 0.f};

  auto stA = [&](int h, int t) {
    stage_half(Ab + ((long long)bm * 256 + h * 128) * lda + t * 64, lda,
               shA + (t & 1) * 16384 + h * 8192, r0, csw, woff);
  };
  auto stB = [&](int h, int t) {
    stage_half(Bb + ((long long)bn * 256 + h * 128) * ldb + t * 64, ldb,
               shB + (t & 1) * 16384 + h * 8192, r0, csw, woff);
  };

  // prologue: tile0 fully + tile1 {A0,A1,B0}; keep tile1's 3 halves in flight
  stA(0, 0); stA(1, 0); stB(0, 0); stB(1, 0);
  if (NT > 1) { stA(0, 1); stA(1, 1); stB(0, 1); WAITV(6); }
  else        { WAITV(0); }
  BARRIER();

  for (int t = 0; t < NT; ++t) {
    const u16* aB = shA + (t & 1) * 16384;
    const u16* bB = shB + (t & 1) * 16384;
    bf16x8 aF[4][2], b01[2][2], b23[2][2];

    // ---- phase 1: read A[i0-3]+B[j0-1]; stage B1(t+1) [other buf]; mfma (0,0)
    #pragma unroll
    for (int i = 0; i < 4; ++i) {
      aF[i][0] = *(const bf16x8*)&aB[(aRow + i * 16) * 64 + ch0];
      aF[i][1] = *(const bf16x8*)&aB[(aRow + i * 16) * 64 + ch1];
    }
    #pragma unroll
    for (int j = 0; j < 2; ++j) {
      b01[j][0] = *(const bf16x8*)&bB[(bRow + j * 16) * 64 + ch0];
      b01[j][1] = *(const bf16x8*)&bB[(bRow + j * 16) * 64 + ch1];
    }
    if (t + 1 < NT) stB(1, t + 1);
    BARRIER(); WAITL0();
    __builtin_amdgcn_s_setprio(1);
    #pragma unroll
    for (int i = 0; i < 4; ++i)
      #pragma unroll
      for (int j = 0; j < 2; ++j) {
        acc[i][j] = MFMA16(aF[i][0], b01[j][0], acc[i][j]);
        acc[i][j] = MFMA16(aF[i][1], b01[j][1], acc[i][j]);
      }
    __builtin_amdgcn_s_setprio(0);
    BARRIER();

    // ---- phase 2: read B[j2-3]; mfma (0,1)
    #pragma unroll
    for (int j = 0; j < 2; ++j) {
      b23[j][0] = *(const bf16x8*)&bB[(bRow + (2 + j) * 16) * 64 + ch0];
      b23[j][1] = *(const bf16x8*)&bB[(bRow + (2 + j) * 16) * 64 + ch1];
    }
    BARRIER(); WAITL0();
    __builtin_amdgcn_s_setprio(1);
    #pragma unroll
    for (int i = 0; i < 4; ++i)
      #pragma unroll
      for (int j = 0; j < 2; ++j) {
        acc[i][2 + j] = MFMA16(aF[i][0], b23[j][0], acc[i][2 + j]);
        acc[i][2 + j] = MFMA16(aF[i][1], b23[j][1], acc[i][2 + j]);
      }
    __builtin_amdgcn_s_setprio(0);
    BARRIER();

    // ---- phase 3: read A[i4-7]; B region of this buf dead -> stage B0(t+2); mfma (1,0)
    #pragma unroll
    for (int i = 0; i < 4; ++i) {
      aF[i][0] = *(const bf16x8*)&aB[(aRow + (4 + i) * 16) * 64 + ch0];
      aF[i][1] = *(const bf16x8*)&aB[(aRow + (4 + i) * 16) * 64 + ch1];
    }
    if (t + 2 < NT) stB(0, t + 2);
    BARRIER(); WAITL0();
    __builtin_amdgcn_s_setprio(1);
    #pragma unroll
    for (int i = 0; i < 4; ++i)
      #pragma unroll
      for (int j = 0; j < 2; ++j) {
        acc[4 + i][j] = MFMA16(aF[i][0], b01[j][0], acc[4 + i][j]);
        acc[4 + i][j] = MFMA16(aF[i][1], b01[j][1], acc[4 + i][j]);
      }
    __builtin_amdgcn_s_setprio(0);
    BARRIER();

    // ---- phase 4: A region of this buf dead -> stage A0,A1(t+2); mfma (1,1);
    //      counted boundary wait: newest 6 loads (t+2's 3 halves) stay in flight
    if (t + 2 < NT) { stA(0, t + 2); stA(1, t + 2); }
    BARRIER(); WAITL0();
    __builtin_amdgcn_s_setprio(1);
    #pragma unroll
    for (int i = 0; i < 4; ++i)
      #pragma unroll
      for (int j = 0; j < 2; ++j) {
        acc[4 + i][2 + j] = MFMA16(aF[i][0], b23[j][0], acc[4 + i][2 + j]);
        acc[4 + i][2 + j] = MFMA16(aF[i][1], b23[j][1], acc[4 + i][2 + j]);
      }
    __builtin_amdgcn_s_setprio(0);
    if (t + 2 < NT) { WAITV(6); } else { WAITV(0); }
    BARRIER();
  }

  // ---- epilogue.  C/D layout (m89): col = lane&15, row = (lane>>4)*4 + reg
  const long long rowb = (long long)bm * 256 + wr * 128 + quad * 4;
  const int colb = bn * 256 + wc * 64 + lc;

  if (MODE == 0) {
    const int region = colb >> 10;           // 0:q 1:k 2:v (tile stays in-region)
    if (region == 0) {
      u16* q = (u16*)Cv;
      #pragma unroll
      for (int i = 0; i < 8; ++i)
        #pragma unroll
        for (int j = 0; j < 4; ++j) {
          const int col = colb + j * 16;
          #pragma unroll
          for (int r = 0; r < 4; ++r) {
            const long long row = rowb + i * 16 + r;
            q[row * ldc + col] = f2b(fmaxf(acc[i][j][r], 0.f) + EPS);
          }
        }
    } else {
      const bool isk = (region == 1);
      const int b = (int)(rowb >> 12);       // batch (256-row tile within batch)
      u16* dst = (isk ? kT : vT) + (long long)b * 1024 * 4096;
      const int nloc = (int)(rowb & 4095);
      #pragma unroll
      for (int j = 0; j < 4; ++j) {
        const int d = colb + j * 16 - region * 1024;
        float s = 0.f;
        #pragma unroll
        for (int i = 0; i < 8; ++i) {
          ushort4 pk;
          #pragma unroll
          for (int r = 0; r < 4; ++r) {
            float v = acc[i][j][r];
            if (isk) { v = fmaxf(v, 0.f) + EPS; s += v; }
            (&pk.x)[r] = f2b(v);
          }
          *(ushort4*)(dst + (long long)d * 4096 + nloc + i * 16) = pk;
        }
        if (isk) {
          s += __shfl_xor(s, 16);            // reduce 4 quads -> 128 n-rows/wave
          s += __shfl_xor(s, 32);
          if (quad == 0) atomicAdd(&ksum[b * 1024 + d], s);
        }
      }
    }
  } else if (MODE == 2) {
    float* out = (float*)Cv + (long long)bz * sC;
    #pragma unroll
    for (int i = 0; i < 8; ++i)
      #pragma unroll
      for (int j = 0; j < 4; ++j) {
        const int col = colb + j * 16;
        const float bj = bias[col];
        #pragma unroll
        for (int r = 0; r < 4; ++r) {
          const long long row = rowb + i * 16 + r;
          out[row * ldc + col] = acc[i][j][r] * zvec[(long long)bz * M + row] + bj;
        }
      }
  } else {
    u16* out = (u16*)Cv + (long long)bz * sC;
    #pragma unroll
    for (int i = 0; i < 8; ++i)
      #pragma unroll
      for (int j = 0; j < 4; ++j) {
        const int col = colb + j * 16;
        #pragma unroll
        for (int r = 0; r < 4; ++r) {
          const long long row = rowb + i * 16 + r;
          out[row * ldc + col] = f2b(acc[i][j][r]);
        }
      }
  }
}

// ---------------------------------------------------------------------------
// 128^2-tile kernel (m97 structure) — kept for GEMM2/2b whose grids are small.
// C = A * B^T.  MODE 1: bf16 out, plain.
// ---------------------------------------------------------------------------
template<int MODE>
__global__ __launch_bounds__(256) void gemm_abT(
    const u16* __restrict__ A, const u16* __restrict__ B, void* __restrict__ Cv,
    int M, int N, int K, int lda, int ldb, int ldc,
    long long sA, long long sB, long long sC,
    const float* __restrict__ zvec, const float* __restrict__ bias,
    u16* __restrict__ kT, u16* __restrict__ vT, float* __restrict__ ksum)
{
  __shared__ u16 lA[128 * 32];
  __shared__ u16 lB[128 * 32];
  const int tid  = threadIdx.x;
  const int wave = tid >> 6, lane = tid & 63;
  const int TN = gridDim.y;
  const int lin = blockIdx.x + gridDim.x * blockIdx.y;
  const int xcd = lin & 7, g = lin >> 3;
  const int bm = (g / TN) * 8 + xcd;
  const int bn = g % TN;
  const int bz = blockIdx.z;
  const u16* Ab = A + (long long)bz * sA;
  const u16* Bb = B + (long long)bz * sB;

  const int c0 = wave * 64 + lane;
  const int c1 = 256 + c0;
  const u16* gA0 = Ab + (long long)(bm * 128 + (c0 >> 2)) * lda + (c0 & 3) * 8;
  const u16* gA1 = Ab + (long long)(bm * 128 + (c1 >> 2)) * lda + (c1 & 3) * 8;
  const u16* gB0 = Bb + (long long)(bn * 128 + (c0 >> 2)) * ldb + (c0 & 3) * 8;
  const u16* gB1 = Bb + (long long)(bn * 128 + (c1 >> 2)) * ldb + (c1 & 3) * 8;
  u16* lA0 = &lA[(wave * 64) * 8];
  u16* lA1 = &lA[(256 + wave * 64) * 8];
  u16* lB0 = &lB[(wave * 64) * 8];
  u16* lB1 = &lB[(256 + wave * 64) * 8];

  const int wm = (wave & 1) * 64, wn = (wave >> 1) * 64;
  const int aoff = (wm + (lane & 15)) * 32 + (lane >> 4) * 8;
  const int boff = (wn + (lane & 15)) * 32 + (lane >> 4) * 8;

  f32x4 acc[4][4];
  #pragma unroll
  for (int i = 0; i < 4; i++)
    #pragma unroll
    for (int j = 0; j < 4; j++) acc[i][j] = f32x4{0.f, 0.f, 0.f, 0.f};

  for (int k0 = 0; k0 < K; k0 += 32) {
    load16_to_lds(gA0 + k0, lA0);
    load16_to_lds(gA1 + k0, lA1);
    load16_to_lds(gB0 + k0, lB0);
    load16_to_lds(gB1 + k0, lB1);
    __syncthreads();
    bf16x8 af[4], bfv[4];
    #pragma unroll
    for (int i = 0; i < 4; i++) af[i]  = *(const bf16x8*)&lA[aoff + i * 16 * 32];
    #pragma unroll
    for (int j = 0; j < 4; j++) bfv[j] = *(const bf16x8*)&lB[boff + j * 16 * 32];
    #pragma unroll
    for (int i = 0; i < 4; i++)
      #pragma unroll
      for (int j = 0; j < 4; j++)
        acc[i][j] = MFMA16(af[i], bfv[j], acc[i][j]);
    __syncthreads();
  }

  const int quad = lane >> 4, lc = lane & 15;
  const int rowb = bm * 128 + wm + quad * 4;
  const int colb = bn * 128 + wn + lc;

  #pragma unroll
  for (int i = 0; i < 4; i++) {
    #pragma unroll
    for (int j = 0; j < 4; j++) {
      const int col = colb + j * 16;
      float bj = 0.f;
      if (MODE == 2) bj = bias[col];
      #pragma unroll
      for (int r = 0; r < 4; r++) {
        const int row = rowb + i * 16 + r;
        float v = acc[i][j][r];
        if (MODE == 1) {
          ((u16*)Cv + (long long)bz * sC)[(long long)row * ldc + col] = f2b(v);
        } else if (MODE == 2) {
          float zz = zvec[(long long)bz * M + row];
          ((float*)Cv + (long long)bz * sC)[(long long)row * ldc + col] = v * zz + bj;
        }
      }
    }
  }
  (void)kT; (void)vT; (void)ksum;
}

// fp32 -> bf16 bulk convert (vectorized, grid-stride)
__global__ void cvt_f32_bf16(const float* __restrict__ s, u16* __restrict__ d, int n4) {
  int i = blockIdx.x * blockDim.x + threadIdx.x;
  int st = gridDim.x * blockDim.x;
  for (; i < n4; i += st) {
    float4 f = ((const float4*)s)[i];
    uint2 o;
    o.x = (unsigned)f2b(f.x) | ((unsigned)f2b(f.y) << 16);
    o.y = (unsigned)f2b(f.z) | ((unsigned)f2b(f.w) << 16);
    ((uint2*)d)[i] = o;
  }
}

__global__ void zero_f32(float* __restrict__ p, int n) {
  int i = blockIdx.x * blockDim.x + threadIdx.x;
  if (i < n) p[i] = 0.f;
}

// z[row] = 1/(q[row,:]·ksum[b,:] + eps); one wave per row; q is [32768][1024]
__global__ void z_kernel(const u16* __restrict__ qbuf, const float* __restrict__ ksum,
                         float* __restrict__ z) {
  const int row  = blockIdx.x * 4 + (threadIdx.x >> 6);
  const int lane = threadIdx.x & 63;
  const int b = row >> 12;
  const uint4* q = (const uint4*)(qbuf + (long long)row * 1024);
  const float* ks = ksum + b * 1024;
  float s = 0.f;
  #pragma unroll
  for (int c = 0; c < 2; c++) {
    int idx = lane + c * 64;
    uint4 d = q[idx];
    unsigned w[4] = {d.x, d.y, d.z, d.w};
    const float* kk = ks + idx * 8;
    #pragma unroll
    for (int qq = 0; qq < 4; qq++)
      s += b2f((u16)(w[qq] & 0xFFFF)) * kk[qq * 2]
         + b2f((u16)(w[qq] >> 16))    * kk[qq * 2 + 1];
  }
  #pragma unroll
  for (int o = 32; o > 0; o >>= 1) s += __shfl_down(s, o);
  if (lane == 0) z[row] = 1.0f / (s + EPS);
}

extern "C" void kernel_launch(void* const* d_in, const int* in_sizes, int n_in,
                              void* d_out, int out_size, void* d_ws, size_t ws_size,
                              hipStream_t stream) {
  const float* x    = (const float*)d_in[0];   // [8,4096,1024]
  const float* Wqkv = (const float*)d_in[1];   // [3072,1024]
  const float* Wout = (const float*)d_in[2];   // [1024,1024]
  const float* bout = (const float*)d_in[3];   // [1024]

  char* ws = (char*)d_ws;                      // ~310.6 MiB
  u16* x_bf    = (u16*)(ws + 0);               // 64 MiB
  u16* qbuf    = (u16*)(ws + 67108864);        // 64 MiB [32768][1024]
  u16* kT      = (u16*)(ws + 134217728);       // 64 MiB [8][1024][4096]
  u16* vT      = (u16*)(ws + 201326592);       // 64 MiB [8][1024][4096]
  u16* wqkv_bf = (u16*)(ws + 268435456);       // 6 MiB
  u16* wout_bf = (u16*)(ws + 274726912);       // 2 MiB
  u16* kv      = (u16*)(ws + 276824064);       // 16 MiB [8][1024][1024]
  u16* kvwT    = (u16*)(ws + 293601280);       // 16 MiB [8][1024][1024]
  float* ksum  = (float*)(ws + 310378496);     // 32 KiB [8][1024]
  float* z     = (float*)(ws + 310411264);     // 128 KiB [32768]

  cvt_f32_bf16<<<4096, 256, 0, stream>>>(x,    x_bf,    33554432 / 4);
  cvt_f32_bf16<<<1024, 256, 0, stream>>>(Wqkv, wqkv_bf,  3145728 / 4);
  cvt_f32_bf16<<<512,  256, 0, stream>>>(Wout, wout_bf,  1048576 / 4);
  zero_f32<<<32, 256, 0, stream>>>(ksum, 8192);

  // GEMM1 (256^2 8-phase): x @ Wqkv^T -> q (n-major) + kT/vT (transposed) + ksum
  gemm256<0><<<dim3(128, 12, 1), 512, 0, stream>>>(
      x_bf, wqkv_bf, qbuf, 32768, 3072, 1024, 1024, 1024, 1024,
      0, 0, 0, nullptr, nullptr, kT, vT, ksum);

  // z = 1/(q·ksum + eps)
  z_kernel<<<8192, 256, 0, stream>>>(qbuf, ksum, z);

  // GEMM2 (batched 8): kv[d][e] = kT_b @ vT_b^T  (K=4096)
  gemm_abT<1><<<dim3(8, 8, 8), 256, 0, stream>>>(
      kT, vT, kv, 1024, 1024, 4096, 4096, 4096, 1024,
      4194304, 4194304, 1048576, nullptr, nullptr, nullptr, nullptr, nullptr);

  // GEMM2b (batched 8): kvwT[f][d] = Wout @ kv_b^T  (K=1024)
  gemm_abT<1><<<dim3(8, 8, 8), 256, 0, stream>>>(
      wout_bf, kv, kvwT, 1024, 1024, 1024, 1024, 1024, 1024,
      0, 1048576, 1048576, nullptr, nullptr, nullptr, nullptr, nullptr);

  // GEMM3 (256^2 8-phase, batched 8): out = z[n]*(q_b @ kvwT_b^T) + b_out, fp32
  gemm256<2><<<dim3(16, 4, 8), 512, 0, stream>>>(
      qbuf, kvwT, d_out, 4096, 1024, 1024, 1024, 1024, 1024,
      4194304, 1048576, 4194304, z, bout, nullptr, nullptr, nullptr);
}